// Round 1
// baseline (479.691 us; speedup 1.0000x reference)
//
#include <hip/hip_runtime.h>

namespace {
constexpr int kB = 256;
constexpr int kT = 1024;
constexpr int kS = 96;
constexpr int kStart = 1;
constexpr float kCF = 3.5f;   // ~ E[log sum_j exp(trans)] keeps exp-space growth ~e^0/step

// ---------------- numerator: sum_t (f[b,t,s_t] + trans[s_t, s_{t-1}]) * mask ----------------
__global__ __launch_bounds__(256) void crf_numerator(
    const float* __restrict__ F, const int* __restrict__ states,
    const float* __restrict__ mask, const float* __restrict__ trans,
    float* __restrict__ wsnum) {
  const int b = blockIdx.x;
  const int tid = threadIdx.x;
  const int* st = states + b * kT;
  const float* Fb = F + (size_t)b * kT * kS;
  const float* mb = mask + b * kT;
  float acc = 0.f;
  for (int t = tid; t < kT; t += 256) {
    const int cu = st[t];
    const int pr = (t > 0) ? st[t - 1] : kStart;
    acc += (Fb[(size_t)t * kS + cu] + trans[cu * kS + pr]) * mb[t];
  }
  __shared__ float red[256];
  red[tid] = acc;
  __syncthreads();
  if (tid < 128) red[tid] += red[tid + 128];
  __syncthreads();
  if (tid < 64) {
    float v = red[tid] + red[tid + 64];
#pragma unroll
    for (int off = 32; off > 0; off >>= 1) v += __shfl_xor(v, off, 64);
    if (tid == 0) wsnum[b] = v;
  }
}

// ---------------- forward recursion in exp space, one block per batch ----------------
// tid = 4*i + g : lane owns output row i (s_new), j-chunk g (24 of 96 s_old).
// Mexp[i][g*24..g*24+23] lives in 24 VGPRs for the whole run.
__global__ __launch_bounds__(384) void crf_forward(
    const float* __restrict__ F, const float* __restrict__ mask,
    const float* __restrict__ trans, const float* __restrict__ wsnum,
    float* __restrict__ out) {
  const int b = blockIdx.x;
  const int tid = threadIdx.x;
  const int g = tid & 3;
  const int i = tid >> 2;   // 0..95

  // p replicated 4x (one copy per g) at word-stride 100 so the 4 broadcast
  // addresses per ds_read_b128 hit disjoint banks: (124*g + 4k) % 32 in {0,28,24,20}+k*4
  __shared__ __align__(16) float pbuf[2][4][100];
  __shared__ __align__(16) float fl[2][16 * kS];   // 16-step feature chunks, double buffered
  __shared__ __align__(16) float ml[kT];           // whole mask row for this batch
  __shared__ float Lsh, rinvsh;

  const float* Fb = F + (size_t)b * kT * kS;

  float mw[24];
#pragma unroll
  for (int k = 0; k < 24; ++k)
    mw[k] = __expf(trans[i * kS + g * 24 + k] - kCF);   // exp(-9999-c) == 0, exact

  // stage chunk0 + chunk1 + mask row
  float4 pf0 = *(const float4*)(Fb + tid * 4);
  float4 pfv = *(const float4*)(Fb + 16 * kS + tid * 4);   // chunk1 held in regs until t=15
  float4 mk4;
  if (tid < 256) mk4 = *(const float4*)(mask + (size_t)b * kT + tid * 4);
  *(float4*)&fl[0][tid * 4] = pf0;
  if (tid < 256) *(float4*)&ml[tid * 4] = mk4;
  pbuf[0][g][i] = (i == kStart) ? 1.0f : 0.0f;   // p0 = exp(alpha0), L = 0
  if (tid == 0) Lsh = 0.0f;
  __syncthreads();

  int cur = 0;
  for (int t = 0; t < kT; ++t) {
    const int nxt = cur ^ 1;
    // issue next-chunk load early (consumed ~15 steps later)
    if ((t & 15) == 0 && t >= 16 && t + 16 < kT)
      pfv = *(const float4*)(Fb + (size_t)(t + 16) * kS + tid * 4);

    // partial dot: rows i, cols g*24..g*24+23
    float acc = 0.f;
    const float* pc = &pbuf[cur][g][g * 24];
#pragma unroll
    for (int k = 0; k < 6; ++k) {
      const float4 pv = *(const float4*)(pc + 4 * k);
      acc = fmaf(mw[4 * k + 0], pv.x, acc);
      acc = fmaf(mw[4 * k + 1], pv.y, acc);
      acc = fmaf(mw[4 * k + 2], pv.z, acc);
      acc = fmaf(mw[4 * k + 3], pv.w, acc);
    }
    // intra-quad reduce: all 4 lanes end with the full row sum
    acc += __shfl_xor(acc, 1, 64);
    acc += __shfl_xor(acc, 2, 64);

    float pnew;
    const float mkv = ml[t];
    if (mkv > 0.f) {
      const float f = fl[(t >> 4) & 1][(t & 15) * kS + i];
      pnew = acc * __expf(f - kCF);
    } else {
      pnew = pbuf[cur][g][i];   // masked step: carry alpha through
    }
    pbuf[nxt][g][i] = pnew;

    // write-late half of the chunk staging
    if ((t & 15) == 15 && t + 16 < kT)
      *(float4*)&fl[((t >> 4) + 1) & 1][tid * 4] = pfv;

    __syncthreads();

    // renorm every 8 steps: p /= max(p), L += log(max)
    if ((t & 7) == 7) {
      if (tid < 32) {
        float m = fmaxf(pbuf[nxt][0][tid],
                  fmaxf(pbuf[nxt][0][tid + 32], pbuf[nxt][0][tid + 64]));
#pragma unroll
        for (int off = 16; off > 0; off >>= 1) m = fmaxf(m, __shfl_xor(m, off, 64));
        if (tid == 0) {
          const float rmax = fmaxf(m, 1e-30f);
          Lsh += __logf(rmax);
          rinvsh = 1.0f / rmax;
        }
      }
      __syncthreads();
      pbuf[nxt][g][i] = pnew * rinvsh;
      __syncthreads();
    }
    cur = nxt;
  }

  // denominator = L + log(sum p); out = denom - numerator
  if (tid < 32) {
    float s = pbuf[cur][0][tid] + pbuf[cur][0][tid + 32] + pbuf[cur][0][tid + 64];
#pragma unroll
    for (int off = 16; off > 0; off >>= 1) s += __shfl_xor(s, off, 64);
    if (tid == 0) out[b] = (Lsh + __logf(s)) - wsnum[b];
  }
}
} // namespace

extern "C" void kernel_launch(void* const* d_in, const int* in_sizes, int n_in,
                              void* d_out, int out_size, void* d_ws, size_t ws_size,
                              hipStream_t stream) {
  const float* F      = (const float*)d_in[0];
  const int*   states = (const int*)d_in[1];
  const float* mask   = (const float*)d_in[2];
  const float* trans  = (const float*)d_in[3];
  float* out   = (float*)d_out;
  float* wsnum = (float*)d_ws;   // B floats of scratch
  hipLaunchKernelGGL(crf_numerator, dim3(kB), dim3(256), 0, stream,
                     F, states, mask, trans, wsnum);
  hipLaunchKernelGGL(crf_forward, dim3(kB), dim3(384), 0, stream,
                     F, mask, trans, wsnum, out);
}

// Round 2
// 326.958 us; speedup vs baseline: 1.4671x; 1.4671x over previous
//
#include <hip/hip_runtime.h>

namespace {
constexpr int kB = 256;
constexpr int kT = 1024;
constexpr int kS = 96;
constexpr int kStart = 1;
constexpr float kCF = 3.5f;   // keeps exp-space growth ~e^0/step
constexpr float kLn2 = 0.69314718055994531f;

// ---------------- numerator: sum_t (f[b,t,s_t] + trans[s_t, s_{t-1}]) * mask ----------------
__global__ __launch_bounds__(256) void crf_numerator(
    const float* __restrict__ F, const int* __restrict__ states,
    const float* __restrict__ mask, const float* __restrict__ trans,
    float* __restrict__ wsnum) {
  const int b = blockIdx.x;
  const int tid = threadIdx.x;
  const int* st = states + b * kT;
  const float* Fb = F + (size_t)b * kT * kS;
  const float* mb = mask + b * kT;
  float acc = 0.f;
  for (int t = tid; t < kT; t += 256) {
    const int cu = st[t];
    const int pr = (t > 0) ? st[t - 1] : kStart;
    acc += (Fb[(size_t)t * kS + cu] + trans[cu * kS + pr]) * mb[t];
  }
  __shared__ float red[256];
  red[tid] = acc;
  __syncthreads();
  if (tid < 128) red[tid] += red[tid + 128];
  __syncthreads();
  if (tid < 64) {
    float v = red[tid] + red[tid + 64];
#pragma unroll
    for (int off = 32; off > 0; off >>= 1) v += __shfl_xor(v, off, 64);
    if (tid == 0) wsnum[b] = v;
  }
}

// ---------------- forward recursion in exp space, one block per batch ----------------
// tid = 2*i + h : thread owns output row i (s_new), half h (48 of 96 s_old).
// Mexp[i][h*48..h*48+47] lives in 48 VGPRs for the whole run.
// One __syncthreads per step; renorm is barrier-free (computed redundantly by
// every thread from the p-values it already read, exact power-of-2 scale).
__global__ __launch_bounds__(192) void crf_forward(
    const float* __restrict__ F, const float* __restrict__ mask,
    const float* __restrict__ trans, const float* __restrict__ wsnum,
    float* __restrict__ out) {
  const int b = blockIdx.x;
  const int tid = threadIdx.x;
  const int h = tid & 1;
  const int i = tid >> 1;   // 0..95

  __shared__ __align__(16) float pbuf[2][kS];
  __shared__ __align__(16) float fl[2][16 * kS];   // 16-step feature chunks, dbuf
  __shared__ __align__(16) float ml[kT];           // whole mask row

  const float* Fb = F + (size_t)b * kT * kS;

  // M row-half in registers (vectorized global read)
  float mw[48];
  {
    const float4* tp = (const float4*)(trans + i * kS + h * 48);
#pragma unroll
    for (int k = 0; k < 12; ++k) {
      const float4 tv = tp[k];
      mw[4 * k + 0] = __expf(tv.x - kCF);
      mw[4 * k + 1] = __expf(tv.y - kCF);
      mw[4 * k + 2] = __expf(tv.z - kCF);
      mw[4 * k + 3] = __expf(tv.w - kCF);
    }
  }

  // stage chunk 0, mask row, p0
  {
    const float4* s = (const float4*)(Fb + tid * 8);
    const float4 a = s[0], c = s[1];
    *(float4*)&fl[0][tid * 8] = a;
    *(float4*)&fl[0][tid * 8 + 4] = c;
    const float4* mb4 = (const float4*)(mask + (size_t)b * kT);
    for (int idx = tid; idx < kT / 4; idx += 192) ((float4*)ml)[idx] = mb4[idx];
    if (h == 0) pbuf[0][i] = (i == kStart) ? 1.0f : 0.0f;
  }
  __syncthreads();

  float Lacc = 0.0f;
  float pown = (i == kStart) ? 1.0f : 0.0f;
  int cur = 0;
  float4 pfa, pfb;

  for (int tc = 0; tc < 64; ++tc) {
    const int fbuf = tc & 1;
    if (tc < 63) {   // issue next chunk's loads early; consumed at tt==15
      const float4* s = (const float4*)(Fb + (size_t)(tc + 1) * 16 * kS + tid * 8);
      pfa = s[0];
      pfb = s[1];
    }
#pragma unroll
    for (int tt = 0; tt < 16; ++tt) {
      const int t = tc * 16 + tt;
      const float* pc = &pbuf[cur][h * 48];
      float4 pv[12];
#pragma unroll
      for (int k = 0; k < 12; ++k) pv[k] = ((const float4*)pc)[k];
      float a0 = 0.f, a1 = 0.f, a2 = 0.f, a3 = 0.f;
#pragma unroll
      for (int k = 0; k < 12; ++k) {
        a0 = fmaf(mw[4 * k + 0], pv[k].x, a0);
        a1 = fmaf(mw[4 * k + 1], pv[k].y, a1);
        a2 = fmaf(mw[4 * k + 2], pv[k].z, a2);
        a3 = fmaf(mw[4 * k + 3], pv[k].w, a3);
      }
      float acc = (a0 + a1) + (a2 + a3);
      acc += __shfl_xor(acc, 1, 64);   // pair (h=0,h=1) -> full row sum

      const float f = fl[fbuf][tt * kS + i];
      const float mkv = ml[t];
      float pnew = (mkv > 0.f) ? acc * __expf(f - kCF) : pown;

      if (((tt + 1) & 7) == 0) {
        // barrier-free renorm: max over the 96 values read this step,
        // identical on every thread; exact power-of-2 scale.
        float4 m4 = pv[0];
#pragma unroll
        for (int k = 1; k < 12; ++k) {
          m4.x = fmaxf(m4.x, pv[k].x);
          m4.y = fmaxf(m4.y, pv[k].y);
          m4.z = fmaxf(m4.z, pv[k].z);
          m4.w = fmaxf(m4.w, pv[k].w);
        }
        float m = fmaxf(fmaxf(m4.x, m4.y), fmaxf(m4.z, m4.w));
        m = fmaxf(m, __shfl_xor(m, 1, 64));
        const int e = (__float_as_int(m) >> 23) & 0xFF;
        const float scale = __int_as_float((254 - e) << 23);   // 2^(127-e), exact
        Lacc += (float)(e - 127) * kLn2;
        pnew *= scale;
      }
      pown = pnew;

      if (tt == 15 && tc < 63) {   // write-late half of the chunk staging
        *(float4*)&fl[fbuf ^ 1][tid * 8] = pfa;
        *(float4*)&fl[fbuf ^ 1][tid * 8 + 4] = pfb;
      }
      if (h == 0) pbuf[cur ^ 1][i] = pnew;
      __syncthreads();
      cur ^= 1;
    }
  }

  // denominator = L + log(sum p); out = denom - numerator
  if (tid < 32) {
    float s = pbuf[cur][tid] + pbuf[cur][tid + 32] + pbuf[cur][tid + 64];
#pragma unroll
    for (int off = 16; off > 0; off >>= 1) s += __shfl_xor(s, off, 64);
    if (tid == 0) out[b] = (Lacc + logf(s)) - wsnum[b];
  }
}
} // namespace

extern "C" void kernel_launch(void* const* d_in, const int* in_sizes, int n_in,
                              void* d_out, int out_size, void* d_ws, size_t ws_size,
                              hipStream_t stream) {
  const float* F      = (const float*)d_in[0];
  const int*   states = (const int*)d_in[1];
  const float* mask   = (const float*)d_in[2];
  const float* trans  = (const float*)d_in[3];
  float* out   = (float*)d_out;
  float* wsnum = (float*)d_ws;   // B floats of scratch
  hipLaunchKernelGGL(crf_numerator, dim3(kB), dim3(256), 0, stream,
                     F, states, mask, trans, wsnum);
  hipLaunchKernelGGL(crf_forward, dim3(kB), dim3(192), 0, stream,
                     F, mask, trans, wsnum, out);
}

// Round 3
// 242.458 us; speedup vs baseline: 1.9785x; 1.3485x over previous
//
#include <hip/hip_runtime.h>

namespace {
constexpr int kB = 256;
constexpr int kT = 1024;
constexpr int kS = 96;
constexpr int kStart = 1;
constexpr float kCF = 3.5f;   // keeps exp-space growth ~e^0/step
constexpr float kLn2 = 0.69314718055994531f;

// workspace layout (floats)
constexpr int OFF_PF = 0;               // [kB][kS] forward p_H
constexpr int OFF_LF = kB * kS;         // [kB]     forward log-scale
constexpr int OFF_WB = OFF_LF + kB;     // [kB][kS] backward w_H
constexpr int OFF_LB = OFF_WB + kB * kS;// [kB]     backward log-scale

__device__ __forceinline__ void renorm96(const float4* pv, float& pnew, float& Lacc) {
  // barrier-free: max over the 96 values read this step (48 local + partner),
  // identical on every thread; exact power-of-2 scale.
  float4 m4 = pv[0];
#pragma unroll
  for (int k = 1; k < 12; ++k) {
    m4.x = fmaxf(m4.x, pv[k].x);
    m4.y = fmaxf(m4.y, pv[k].y);
    m4.z = fmaxf(m4.z, pv[k].z);
    m4.w = fmaxf(m4.w, pv[k].w);
  }
  float m = fmaxf(fmaxf(m4.x, m4.y), fmaxf(m4.z, m4.w));
  m = fmaxf(m, __shfl_xor(m, 1, 64));
  const int e = (__float_as_int(m) >> 23) & 0xFF;
  const float scale = __int_as_float((254 - e) << 23);   // 2^(127-e), exact
  Lacc += (float)(e - 127) * kLn2;
  pnew *= scale;
}

// Half-chain kernel: blocks [0,256) = forward over t=0..511 (p' = D M p),
// blocks [256,512) = backward over t=1023..512 (w' = M^T D w).
// tid = 2*i + h : thread owns state-row i, half h (48 of 96 columns).
__global__ __launch_bounds__(192) void crf_halves(
    const float* __restrict__ F, const float* __restrict__ mask,
    const float* __restrict__ trans, float* __restrict__ ws) {
  const bool bwd = blockIdx.x >= kB;
  const int b = bwd ? (blockIdx.x - kB) : blockIdx.x;
  const int tid = threadIdx.x;
  const int h = tid & 1;
  const int i = tid >> 1;   // 0..95

  __shared__ __align__(16) float pbuf[2][kS];
  __shared__ __align__(16) float fl[2][16 * kS];   // 16-step feature chunks, dbuf
  __shared__ __align__(16) float ml[kT];           // whole mask row

  const float* Fb = F + (size_t)b * kT * kS;

  // matrix fragment in registers: fwd = row i of M, bwd = row i of M^T (col i of M)
  float mw[48];
  if (!bwd) {
    const float4* tp = (const float4*)(trans + i * kS + h * 48);
#pragma unroll
    for (int k = 0; k < 12; ++k) {
      const float4 tv = tp[k];
      mw[4 * k + 0] = __expf(tv.x - kCF);
      mw[4 * k + 1] = __expf(tv.y - kCF);
      mw[4 * k + 2] = __expf(tv.z - kCF);
      mw[4 * k + 3] = __expf(tv.w - kCF);
    }
  } else {
#pragma unroll
    for (int k = 0; k < 48; ++k)
      mw[k] = __expf(trans[(h * 48 + k) * kS + i] - kCF);
  }

  const int gb0 = bwd ? (kT - 16) : 0;
  const int gstep = bwd ? -16 : 16;

  // stage chunk 0, mask row, p0
  {
    const float4* s = (const float4*)(Fb + (size_t)gb0 * kS + tid * 8);
    const float4 a = s[0], c4 = s[1];
    *(float4*)&fl[0][tid * 8] = a;
    *(float4*)&fl[0][tid * 8 + 4] = c4;
    const float4* mb4 = (const float4*)(mask + (size_t)b * kT);
    for (int idx = tid; idx < kT / 4; idx += 192) ((float4*)ml)[idx] = mb4[idx];
    if (!bwd && h == 0) pbuf[0][i] = (i == kStart) ? 1.0f : 0.0f;
  }
  __syncthreads();

  float Lacc = 0.0f;
  float pown = bwd ? 1.0f : ((i == kStart) ? 1.0f : 0.0f);
  int cur = 0;
  float4 pfa, pfb;

  for (int tc = 0; tc < 32; ++tc) {
    const int fbuf = tc & 1;
    if (tc < 31) {   // issue next chunk's loads early; consumed at tt==15
      const float4* s =
          (const float4*)(Fb + (size_t)(gb0 + (tc + 1) * gstep) * kS + tid * 8);
      pfa = s[0];
      pfb = s[1];
    }
#pragma unroll
    for (int tt = 0; tt < 16; ++tt) {
      const int tl = tc * 16 + tt;
      const int t = bwd ? (kT - 1 - tl) : tl;
      const float f = fl[fbuf][(bwd ? (15 - tt) : tt) * kS + i];
      const float mkv = ml[t];

      if (!bwd) {
        // read p, matvec, then emission scale
        const float* pc = &pbuf[cur][h * 48];
        float4 pv[12];
#pragma unroll
        for (int k = 0; k < 12; ++k) pv[k] = ((const float4*)pc)[k];
        float a0 = 0.f, a1 = 0.f, a2 = 0.f, a3 = 0.f;
#pragma unroll
        for (int k = 0; k < 12; ++k) {
          a0 = fmaf(mw[4 * k + 0], pv[k].x, a0);
          a1 = fmaf(mw[4 * k + 1], pv[k].y, a1);
          a2 = fmaf(mw[4 * k + 2], pv[k].z, a2);
          a3 = fmaf(mw[4 * k + 3], pv[k].w, a3);
        }
        float acc = (a0 + a1) + (a2 + a3);
        acc += __shfl_xor(acc, 1, 64);
        float pnew = (mkv > 0.f) ? acc * __expf(f - kCF) : pown;
        if (((tt + 1) & 7) == 0) renorm96(pv, pnew, Lacc);
        if (tt == 15 && tc < 31) {
          *(float4*)&fl[fbuf ^ 1][tid * 8] = pfa;
          *(float4*)&fl[fbuf ^ 1][tid * 8 + 4] = pfb;
        }
        if (h == 0) pbuf[cur ^ 1][i] = pnew;
        __syncthreads();
        pown = pnew;
      } else {
        // emission scale on input, write, then matvec with M^T
        const float u = pown * __expf(f - kCF);
        if (h == 0) pbuf[cur ^ 1][i] = u;
        if (tt == 15 && tc < 31) {
          *(float4*)&fl[fbuf ^ 1][tid * 8] = pfa;
          *(float4*)&fl[fbuf ^ 1][tid * 8 + 4] = pfb;
        }
        __syncthreads();
        const float* pc = &pbuf[cur ^ 1][h * 48];
        float4 pv[12];
#pragma unroll
        for (int k = 0; k < 12; ++k) pv[k] = ((const float4*)pc)[k];
        float a0 = 0.f, a1 = 0.f, a2 = 0.f, a3 = 0.f;
#pragma unroll
        for (int k = 0; k < 12; ++k) {
          a0 = fmaf(mw[4 * k + 0], pv[k].x, a0);
          a1 = fmaf(mw[4 * k + 1], pv[k].y, a1);
          a2 = fmaf(mw[4 * k + 2], pv[k].z, a2);
          a3 = fmaf(mw[4 * k + 3], pv[k].w, a3);
        }
        float acc = (a0 + a1) + (a2 + a3);
        acc += __shfl_xor(acc, 1, 64);
        float pnew = (mkv > 0.f) ? acc : pown;
        if (((tt + 1) & 7) == 0) renorm96(pv, pnew, Lacc);
        pown = pnew;
      }
      cur ^= 1;
    }
  }

  if (h == 0) ws[(bwd ? OFF_WB : OFF_PF) + b * kS + i] = pown;
  if (tid == 0) ws[(bwd ? OFF_LB : OFF_LF) + b] = Lacc;
}

// finalize: numerator (gather-sum, L3-hot) + combine halves
__global__ __launch_bounds__(256) void crf_finalize(
    const float* __restrict__ F, const int* __restrict__ states,
    const float* __restrict__ mask, const float* __restrict__ trans,
    const float* __restrict__ ws, float* __restrict__ out) {
  const int b = blockIdx.x;
  const int tid = threadIdx.x;
  const int* st = states + b * kT;
  const float* Fb = F + (size_t)b * kT * kS;
  const float* mb = mask + b * kT;

  float acc = 0.f;
  for (int t = tid; t < kT; t += 256) {
    const int cu = st[t];
    const int pr = (t > 0) ? st[t - 1] : kStart;
    acc += (Fb[(size_t)t * kS + cu] + trans[cu * kS + pr]) * mb[t];
  }
  __shared__ float red[256];
  red[tid] = acc;
  __syncthreads();
  if (tid < 128) red[tid] += red[tid + 128];
  __syncthreads();
  float numv = 0.f;
  if (tid < 64) {
    float v = red[tid] + red[tid + 64];
#pragma unroll
    for (int off = 32; off > 0; off >>= 1) v += __shfl_xor(v, off, 64);
    numv = v;   // valid on tid 0
  }
  __syncthreads();

  // dot(p_H, w_H)
  float dv = 0.f;
  if (tid < kS) dv = ws[OFF_PF + b * kS + tid] * ws[OFF_WB + b * kS + tid];
  red[tid] = dv;
  __syncthreads();
  if (tid < 128) red[tid] += red[tid + 128];
  __syncthreads();
  if (tid < 64) {
    float v = red[tid] + red[tid + 64];
#pragma unroll
    for (int off = 32; off > 0; off >>= 1) v += __shfl_xor(v, off, 64);
    if (tid == 0)
      out[b] = (ws[OFF_LF + b] + ws[OFF_LB + b] + logf(v)) - numv;
  }
}
} // namespace

extern "C" void kernel_launch(void* const* d_in, const int* in_sizes, int n_in,
                              void* d_out, int out_size, void* d_ws, size_t ws_size,
                              hipStream_t stream) {
  const float* F      = (const float*)d_in[0];
  const int*   states = (const int*)d_in[1];
  const float* mask   = (const float*)d_in[2];
  const float* trans  = (const float*)d_in[3];
  float* out = (float*)d_out;
  float* ws  = (float*)d_ws;
  hipLaunchKernelGGL(crf_halves, dim3(2 * kB), dim3(192), 0, stream,
                     F, mask, trans, ws);
  hipLaunchKernelGGL(crf_finalize, dim3(kB), dim3(256), 0, stream,
                     F, states, mask, trans, ws, out);
}